// Round 1
// baseline (798.534 us; speedup 1.0000x reference)
//
#include <hip/hip_runtime.h>
#include <math.h>

#define Bn 128
#define Nn 1000
#define Tn 50
#define En 32000
#define Rn 4
#define FSn 43
#define NSELn 500

// ---------------------------------------------------------------------------
// Kernel 1: fused temporal feature extraction.
// One thread per (b, n). Block = 64 threads = 64 nodes of one batch b.
// LDS: obs tile [3][64][51] (pad 50->51: stride 51 is odd -> 2-way bank alias, free).
// Produces x[b][n][43] = [short(20), mid(20), long(3)].
// ---------------------------------------------------------------------------
__global__ __launch_bounds__(64) void k_temporal(
    const float* __restrict__ obs,
    const float* __restrict__ w_s1, const float* __restrict__ b_s1,
    const float* __restrict__ w_s2, const float* __restrict__ b_s2,
    const float* __restrict__ w_m1, const float* __restrict__ b_m1,
    const float* __restrict__ w_m2, const float* __restrict__ b_m2,
    float* __restrict__ x)
{
    __shared__ float obs_s[3][64][51];

    const int b    = blockIdx.x;
    const int n0   = blockIdx.y * 64;
    const int lane = threadIdx.x;
    const int nrows = (Nn - n0) < 64 ? (Nn - n0) : 64;

    for (int c = 0; c < 3; ++c) {
        const float* srcp = obs + ((size_t)(b * 3 + c)) * (Nn * Tn) + (size_t)n0 * Tn;
        for (int idx = lane; idx < nrows * Tn; idx += 64) {
            obs_s[c][idx / Tn][idx % Tn] = srcp[idx];
        }
    }
    __syncthreads();

    const int n = n0 + lane;
    if (n >= Nn) return;

    float* xp = x + ((size_t)b * Nn + n) * FSn;

    // ---- long path: relu(max over t) ----
    #pragma unroll
    for (int c = 0; c < 3; ++c) {
        float m = obs_s[c][lane][0];
        #pragma unroll 1
        for (int t = 1; t < Tn; ++t) m = fmaxf(m, obs_s[c][lane][t]);
        xp[40 + c] = fmaxf(m, 0.f);
    }

    // ---- short path: conv(k=3) -> relu -> conv(k=48) -> relu ----
    {
        float w1[27];
        #pragma unroll
        for (int k = 0; k < 27; ++k) w1[k] = w_s1[k];
        float bs1_0 = b_s1[0], bs1_1 = b_s1[1], bs1_2 = b_s1[2];

        float acc[20];
        #pragma unroll
        for (int o = 0; o < 20; ++o) acc[o] = b_s2[o];

        #pragma unroll 1
        for (int t = 0; t < 48; ++t) {
            float ov[9];
            #pragma unroll
            for (int c = 0; c < 3; ++c)
                #pragma unroll
                for (int d = 0; d < 3; ++d)
                    ov[c * 3 + d] = obs_s[c][lane][t + d];

            float v[3];
            #pragma unroll
            for (int i = 0; i < 3; ++i) {
                float s = (i == 0) ? bs1_0 : (i == 1) ? bs1_1 : bs1_2;
                #pragma unroll
                for (int c = 0; c < 3; ++c)
                    #pragma unroll
                    for (int d = 0; d < 3; ++d)
                        s += ov[c * 3 + d] * w1[(i * 3 + c) * 3 + d];
                v[i] = fmaxf(s, 0.f);
            }
            #pragma unroll
            for (int o = 0; o < 20; ++o) {
                float a = acc[o];
                a += v[0] * w_s2[(o * 3 + 0) * 48 + t];
                a += v[1] * w_s2[(o * 3 + 1) * 48 + t];
                a += v[2] * w_s2[(o * 3 + 2) * 48 + t];
                acc[o] = a;
            }
        }
        #pragma unroll
        for (int o = 0; o < 20; ++o) xp[o] = fmaxf(acc[o], 0.f);
    }

    // ---- mid path: conv(k=21) -> relu -> conv(k=30) -> relu ----
    {
        float bm1_0 = b_m1[0], bm1_1 = b_m1[1], bm1_2 = b_m1[2];
        float acc[20];
        #pragma unroll
        for (int o = 0; o < 20; ++o) acc[o] = b_m2[o];

        #pragma unroll 1
        for (int t = 0; t < 30; ++t) {
            float v0 = bm1_0, v1 = bm1_1, v2 = bm1_2;
            #pragma unroll
            for (int c = 0; c < 3; ++c) {
                #pragma unroll
                for (int d = 0; d < 21; ++d) {
                    float ov = obs_s[c][lane][t + d];
                    v0 += ov * w_m1[(0 * 3 + c) * 21 + d];
                    v1 += ov * w_m1[(1 * 3 + c) * 21 + d];
                    v2 += ov * w_m1[(2 * 3 + c) * 21 + d];
                }
            }
            v0 = fmaxf(v0, 0.f); v1 = fmaxf(v1, 0.f); v2 = fmaxf(v2, 0.f);
            #pragma unroll
            for (int o = 0; o < 20; ++o) {
                float a = acc[o];
                a += v0 * w_m2[(o * 3 + 0) * 30 + t];
                a += v1 * w_m2[(o * 3 + 1) * 30 + t];
                a += v2 * w_m2[(o * 3 + 2) * 30 + t];
                acc[o] = a;
            }
        }
        #pragma unroll
        for (int o = 0; o < 20; ++o) xp[20 + o] = fmaxf(acc[o], 0.f);
    }
}

// ---------------------------------------------------------------------------
// CSR build for the edge list (grouped by segment = dst*R + edge_type)
// ---------------------------------------------------------------------------
__global__ void k_zero(int* __restrict__ cnt, int* __restrict__ pos)
{
    int i = blockIdx.x * blockDim.x + threadIdx.x;
    if (i < 4096) { cnt[i] = 0; pos[i] = 0; }
}

__global__ void k_count(const int* __restrict__ ei, const int* __restrict__ et,
                        int* __restrict__ cnt)
{
    int e = blockIdx.x * blockDim.x + threadIdx.x;
    if (e < En) {
        int dst = ei[En + e];
        atomicAdd(&cnt[dst * Rn + et[e]], 1);
    }
}

__global__ __launch_bounds__(1024) void k_scan(const int* __restrict__ cnt,
                                               int* __restrict__ off)
{
    __shared__ int sums[1024];
    int tid = threadIdx.x;
    int base = tid * 4;
    int c[4];
    int ts = 0;
    #pragma unroll
    for (int k = 0; k < 4; ++k) {
        int i = base + k;
        c[k] = (i < Nn * Rn) ? cnt[i] : 0;
        ts += c[k];
    }
    sums[tid] = ts;
    __syncthreads();
    for (int d = 1; d < 1024; d <<= 1) {
        int t = 0;
        if (tid >= d) t = sums[tid - d];
        __syncthreads();
        sums[tid] += t;
        __syncthreads();
    }
    int excl = sums[tid] - ts;
    #pragma unroll
    for (int k = 0; k < 4; ++k) {
        int i = base + k;
        off[i] = excl;
        excl += c[k];
    }
}

__global__ void k_fill(const int* __restrict__ ei, const int* __restrict__ et,
                       const int* __restrict__ off, int* __restrict__ pos,
                       int* __restrict__ csr)
{
    int e = blockIdx.x * blockDim.x + threadIdx.x;
    if (e < En) {
        int src = ei[e];
        int dst = ei[En + e];
        int seg = dst * Rn + et[e];
        int p = atomicAdd(&pos[seg], 1);
        csr[off[seg] + p] = src;
    }
}

// ---------------------------------------------------------------------------
// Kernel 2: graph aggregation + root transform + leaky-relu.
// gout[b,dst,:] = leaky( sum_r inv_r * (sum_{e in (dst,r)} x[b,src_e,:]) @ w_rel[r]
//                        + x[b,dst,:] @ w_root + b_g )
// One wave per (b,dst); lane = feature index on gather, output index on matvec.
// ---------------------------------------------------------------------------
__global__ __launch_bounds__(1024) void k_agg(
    const float* __restrict__ x,
    const float* __restrict__ w_rel, const float* __restrict__ w_root,
    const float* __restrict__ b_g,
    const int* __restrict__ csr, const int* __restrict__ off,
    const int* __restrict__ cnt,
    float* __restrict__ gout)
{
    __shared__ float w_s[5 * FSn * FSn];   // [r][f][g], r=4 is w_root
    __shared__ float bg_s[FSn];

    const int tid = threadIdx.x;
    for (int idx = tid; idx < 5 * FSn * FSn; idx += 1024) {
        w_s[idx] = (idx < 4 * FSn * FSn) ? w_rel[idx] : w_root[idx - 4 * FSn * FSn];
    }
    if (tid < FSn) bg_s[tid] = b_g[tid];
    __syncthreads();

    const int lane = tid & 63;
    const int pair = blockIdx.x * 16 + (tid >> 6);    // b*N + dst
    const int b = pair / Nn;
    const int dst = pair - b * Nn;
    const bool act = lane < FSn;
    const int g = act ? lane : 0;

    const float* xb = x + (size_t)b * (Nn * FSn);

    float sr[4];
    float iv[4];
    #pragma unroll
    for (int r = 0; r < 4; ++r) {
        int seg = dst * Rn + r;
        int o0 = off[seg];
        int c  = cnt[seg];
        float s = 0.f;
        for (int j = 0; j < c; ++j) {
            int sn = csr[o0 + j];
            s += act ? xb[sn * FSn + lane] : 0.f;
        }
        iv[r] = (c > 0) ? (1.f / (float)c) : 0.f;
        sr[r] = s;
    }
    #pragma unroll
    for (int r = 0; r < 4; ++r) sr[r] *= iv[r];

    float xr = act ? xb[dst * FSn + lane] : 0.f;
    float pre = act ? bg_s[g] : 0.f;

    for (int f = 0; f < FSn; ++f) {
        float a0 = __shfl(sr[0], f);
        float a1 = __shfl(sr[1], f);
        float a2 = __shfl(sr[2], f);
        float a3 = __shfl(sr[3], f);
        float ax = __shfl(xr, f);
        const int wb = f * FSn + g;
        pre += a0 * w_s[0 * FSn * FSn + wb];
        pre += a1 * w_s[1 * FSn * FSn + wb];
        pre += a2 * w_s[2 * FSn * FSn + wb];
        pre += a3 * w_s[3 * FSn * FSn + wb];
        pre += ax * w_s[4 * FSn * FSn + wb];
    }

    if (act) {
        gout[(size_t)pair * FSn + lane] = (pre > 0.f) ? pre : 0.01f * pre;
    }
}

// ---------------------------------------------------------------------------
// Kernel 3: final projection over selected nodes + softmax over 501 logits.
// One block per batch element.
// ---------------------------------------------------------------------------
__global__ __launch_bounds__(512) void k_final(
    const float* __restrict__ x, const float* __restrict__ gout,
    const float* __restrict__ la,
    const float* __restrict__ w_fin, const float* __restrict__ b_fin,
    const int* __restrict__ sel,
    float* __restrict__ out)
{
    __shared__ float wf_s[87];
    __shared__ float logits[501];
    __shared__ float red[512];

    const int b = blockIdx.x;
    const int tid = threadIdx.x;

    if (tid < 87) wf_s[tid] = w_fin[tid];
    if (tid == 0) logits[0] = 0.f;
    __syncthreads();

    if (tid < NSELn) {
        int n = sel[tid];
        const float* xp = x + ((size_t)b * Nn + n) * FSn;
        const float* gp = gout + ((size_t)b * Nn + n) * FSn;
        float s = b_fin[0] + wf_s[0] * la[b * (NSELn + 1) + 1 + tid];
        #pragma unroll
        for (int c = 0; c < FSn; ++c) s += wf_s[1 + c] * xp[c];
        #pragma unroll
        for (int c = 0; c < FSn; ++c) s += wf_s[44 + c] * gp[c];
        logits[1 + tid] = s;
    }
    __syncthreads();

    // max reduce over 501
    red[tid] = (tid < 501) ? logits[tid] : -1e30f;
    __syncthreads();
    for (int s = 256; s > 0; s >>= 1) {
        if (tid < s) red[tid] = fmaxf(red[tid], red[tid + s]);
        __syncthreads();
    }
    float mx = red[0];
    __syncthreads();

    float e = 0.f;
    if (tid < 501) e = expf(logits[tid] - mx);
    red[tid] = e;
    __syncthreads();
    for (int s = 256; s > 0; s >>= 1) {
        if (tid < s) red[tid] += red[tid + s];
        __syncthreads();
    }
    float tot = red[0];

    if (tid < 501) out[(size_t)b * 501 + tid] = e / tot;
}

// ---------------------------------------------------------------------------
extern "C" void kernel_launch(void* const* d_in, const int* in_sizes, int n_in,
                              void* d_out, int out_size, void* d_ws, size_t ws_size,
                              hipStream_t stream)
{
    const float* obs    = (const float*)d_in[0];
    const float* la     = (const float*)d_in[1];
    const float* w_s1   = (const float*)d_in[2];
    const float* b_s1   = (const float*)d_in[3];
    const float* w_s2   = (const float*)d_in[4];
    const float* b_s2   = (const float*)d_in[5];
    const float* w_m1   = (const float*)d_in[6];
    const float* b_m1   = (const float*)d_in[7];
    const float* w_m2   = (const float*)d_in[8];
    const float* b_m2   = (const float*)d_in[9];
    const float* w_rel  = (const float*)d_in[10];
    const float* w_root = (const float*)d_in[11];
    const float* b_g    = (const float*)d_in[12];
    const float* w_fin  = (const float*)d_in[13];
    const float* b_fin  = (const float*)d_in[14];
    const int*   ei     = (const int*)d_in[15];
    const int*   et     = (const int*)d_in[16];
    const int*   sel    = (const int*)d_in[17];
    float*       out    = (float*)d_out;

    float* x    = (float*)d_ws;                 // B*N*43 = 5,504,000 floats
    float* gout = x + 5504000;                  // B*N*43
    int*   cnt  = (int*)(gout + 5504000);       // 4096
    int*   off  = cnt + 4096;                   // 4096
    int*   pos  = off + 4096;                   // 4096
    int*   csr  = pos + 4096;                   // 32000

    hipLaunchKernelGGL(k_zero,  dim3(16),  dim3(256), 0, stream, cnt, pos);
    hipLaunchKernelGGL(k_count, dim3((En + 255) / 256), dim3(256), 0, stream, ei, et, cnt);
    hipLaunchKernelGGL(k_scan,  dim3(1),   dim3(1024), 0, stream, cnt, off);
    hipLaunchKernelGGL(k_fill,  dim3((En + 255) / 256), dim3(256), 0, stream, ei, et, off, pos, csr);

    hipLaunchKernelGGL(k_temporal, dim3(Bn, (Nn + 63) / 64), dim3(64), 0, stream,
                       obs, w_s1, b_s1, w_s2, b_s2, w_m1, b_m1, w_m2, b_m2, x);

    hipLaunchKernelGGL(k_agg, dim3((Bn * Nn) / 16), dim3(1024), 0, stream,
                       x, w_rel, w_root, b_g, csr, off, cnt, gout);

    hipLaunchKernelGGL(k_final, dim3(Bn), dim3(512), 0, stream,
                       x, gout, la, w_fin, b_fin, sel, out);
}

// Round 2
// 353.309 us; speedup vs baseline: 2.2602x; 2.2602x over previous
//
#include <hip/hip_runtime.h>
#include <math.h>

#define Bn 128
#define Nn 1000
#define Tn 50
#define En 32000
#define Rn 4
#define FSn 43
#define NSELn 500
#define NFtot (Nn * FSn)   // 43000

// ---------------------------------------------------------------------------
// Kernel 1: fused temporal feature extraction (unchanged from round 1).
// One thread per (b, n). Produces x[b][n][43] b-major.
// ---------------------------------------------------------------------------
__global__ __launch_bounds__(64) void k_temporal(
    const float* __restrict__ obs,
    const float* __restrict__ w_s1, const float* __restrict__ b_s1,
    const float* __restrict__ w_s2, const float* __restrict__ b_s2,
    const float* __restrict__ w_m1, const float* __restrict__ b_m1,
    const float* __restrict__ w_m2, const float* __restrict__ b_m2,
    float* __restrict__ x)
{
    __shared__ float obs_s[3][64][51];

    const int b    = blockIdx.x;
    const int n0   = blockIdx.y * 64;
    const int lane = threadIdx.x;
    const int nrows = (Nn - n0) < 64 ? (Nn - n0) : 64;

    for (int c = 0; c < 3; ++c) {
        const float* srcp = obs + ((size_t)(b * 3 + c)) * (Nn * Tn) + (size_t)n0 * Tn;
        for (int idx = lane; idx < nrows * Tn; idx += 64) {
            obs_s[c][idx / Tn][idx % Tn] = srcp[idx];
        }
    }
    __syncthreads();

    const int n = n0 + lane;
    if (n >= Nn) return;

    float* xp = x + ((size_t)b * Nn + n) * FSn;

    // ---- long path ----
    #pragma unroll
    for (int c = 0; c < 3; ++c) {
        float m = obs_s[c][lane][0];
        #pragma unroll 1
        for (int t = 1; t < Tn; ++t) m = fmaxf(m, obs_s[c][lane][t]);
        xp[40 + c] = fmaxf(m, 0.f);
    }

    // ---- short path ----
    {
        float w1[27];
        #pragma unroll
        for (int k = 0; k < 27; ++k) w1[k] = w_s1[k];
        float bs1_0 = b_s1[0], bs1_1 = b_s1[1], bs1_2 = b_s1[2];

        float acc[20];
        #pragma unroll
        for (int o = 0; o < 20; ++o) acc[o] = b_s2[o];

        #pragma unroll 1
        for (int t = 0; t < 48; ++t) {
            float ov[9];
            #pragma unroll
            for (int c = 0; c < 3; ++c)
                #pragma unroll
                for (int d = 0; d < 3; ++d)
                    ov[c * 3 + d] = obs_s[c][lane][t + d];

            float v[3];
            #pragma unroll
            for (int i = 0; i < 3; ++i) {
                float s = (i == 0) ? bs1_0 : (i == 1) ? bs1_1 : bs1_2;
                #pragma unroll
                for (int c = 0; c < 3; ++c)
                    #pragma unroll
                    for (int d = 0; d < 3; ++d)
                        s += ov[c * 3 + d] * w1[(i * 3 + c) * 3 + d];
                v[i] = fmaxf(s, 0.f);
            }
            #pragma unroll
            for (int o = 0; o < 20; ++o) {
                float a = acc[o];
                a += v[0] * w_s2[(o * 3 + 0) * 48 + t];
                a += v[1] * w_s2[(o * 3 + 1) * 48 + t];
                a += v[2] * w_s2[(o * 3 + 2) * 48 + t];
                acc[o] = a;
            }
        }
        #pragma unroll
        for (int o = 0; o < 20; ++o) xp[o] = fmaxf(acc[o], 0.f);
    }

    // ---- mid path ----
    {
        float bm1_0 = b_m1[0], bm1_1 = b_m1[1], bm1_2 = b_m1[2];
        float acc[20];
        #pragma unroll
        for (int o = 0; o < 20; ++o) acc[o] = b_m2[o];

        #pragma unroll 1
        for (int t = 0; t < 30; ++t) {
            float v0 = bm1_0, v1 = bm1_1, v2 = bm1_2;
            #pragma unroll
            for (int c = 0; c < 3; ++c) {
                #pragma unroll
                for (int d = 0; d < 21; ++d) {
                    float ov = obs_s[c][lane][t + d];
                    v0 += ov * w_m1[(0 * 3 + c) * 21 + d];
                    v1 += ov * w_m1[(1 * 3 + c) * 21 + d];
                    v2 += ov * w_m1[(2 * 3 + c) * 21 + d];
                }
            }
            v0 = fmaxf(v0, 0.f); v1 = fmaxf(v1, 0.f); v2 = fmaxf(v2, 0.f);
            #pragma unroll
            for (int o = 0; o < 20; ++o) {
                float a = acc[o];
                a += v0 * w_m2[(o * 3 + 0) * 30 + t];
                a += v1 * w_m2[(o * 3 + 1) * 30 + t];
                a += v2 * w_m2[(o * 3 + 2) * 30 + t];
                acc[o] = a;
            }
        }
        #pragma unroll
        for (int o = 0; o < 20; ++o) xp[20 + o] = fmaxf(acc[o], 0.f);
    }
}

// ---------------------------------------------------------------------------
// Transpose x[b][nf] (128 x 43000) -> xT[nf][b] (43000 x 128)
// ---------------------------------------------------------------------------
__global__ __launch_bounds__(256) void k_transpose(const float* __restrict__ x,
                                                   float* __restrict__ xT)
{
    __shared__ float tile[64][129];
    const int c0  = blockIdx.x * 64;
    const int tid = threadIdx.x;

    const int j  = tid & 63;
    const int bs = tid >> 6;
    for (int bb = bs; bb < Bn; bb += 4) {
        int c = c0 + j;
        if (c < NFtot) tile[j][bb] = x[(size_t)bb * NFtot + c];
    }
    __syncthreads();

    const int b  = tid & 127;
    for (int jj = (tid >> 7); jj < 64; jj += 2) {
        int c = c0 + jj;
        if (c < NFtot) xT[(size_t)c * Bn + b] = tile[jj][b];
    }
}

// ---------------------------------------------------------------------------
// CSR build (unchanged)
// ---------------------------------------------------------------------------
__global__ void k_zero(int* __restrict__ cnt, int* __restrict__ pos)
{
    int i = blockIdx.x * blockDim.x + threadIdx.x;
    if (i < 4096) { cnt[i] = 0; pos[i] = 0; }
}

__global__ void k_count(const int* __restrict__ ei, const int* __restrict__ et,
                        int* __restrict__ cnt)
{
    int e = blockIdx.x * blockDim.x + threadIdx.x;
    if (e < En) {
        int dst = ei[En + e];
        atomicAdd(&cnt[dst * Rn + et[e]], 1);
    }
}

__global__ __launch_bounds__(1024) void k_scan(const int* __restrict__ cnt,
                                               int* __restrict__ off)
{
    __shared__ int sums[1024];
    int tid = threadIdx.x;
    int base = tid * 4;
    int c[4];
    int ts = 0;
    #pragma unroll
    for (int k = 0; k < 4; ++k) {
        int i = base + k;
        c[k] = (i < Nn * Rn) ? cnt[i] : 0;
        ts += c[k];
    }
    sums[tid] = ts;
    __syncthreads();
    for (int d = 1; d < 1024; d <<= 1) {
        int t = 0;
        if (tid >= d) t = sums[tid - d];
        __syncthreads();
        sums[tid] += t;
        __syncthreads();
    }
    int excl = sums[tid] - ts;
    #pragma unroll
    for (int k = 0; k < 4; ++k) {
        int i = base + k;
        off[i] = excl;
        excl += c[k];
    }
}

__global__ void k_fill(const int* __restrict__ ei, const int* __restrict__ et,
                       const int* __restrict__ off, int* __restrict__ pos,
                       int* __restrict__ csr)
{
    int e = blockIdx.x * blockDim.x + threadIdx.x;
    if (e < En) {
        int src = ei[e];
        int dst = ei[En + e];
        int seg = dst * Rn + et[e];
        int p = atomicAdd(&pos[seg], 1);
        csr[off[seg] + p] = src;
    }
}

// ---------------------------------------------------------------------------
// Kernel 2 (new): gather + relational transform + root + leaky + final
// projection, fused. One block per SELECTED dst node; lanes = batch b.
// 512 threads = 4 f-groups x 128 b.
// Writes logitT[i][b] (transposed logits).
// ---------------------------------------------------------------------------
__global__ __launch_bounds__(512) void k_gather(
    const float* __restrict__ xT,
    const float* __restrict__ w_rel, const float* __restrict__ w_root,
    const float* __restrict__ b_g,
    const float* __restrict__ w_fin, const float* __restrict__ b_fin,
    const float* __restrict__ la,
    const int* __restrict__ csr, const int* __restrict__ off,
    const int* __restrict__ cnt, const int* __restrict__ sel,
    float* __restrict__ logitT)
{
    __shared__ int   srcs[Rn][128];
    __shared__ int   scnt[Rn];     // clamped count (loop bound)
    __shared__ int   tcnt[Rn];     // true count (for mean)
    __shared__ float red[FSn + 1][Bn];   // 44 x 128 reduction buffer

    const int i   = blockIdx.x;
    const int dst = sel[i];
    const int tid = threadIdx.x;
    const int fs  = tid >> 7;      // 0..3  f-group
    const int b   = tid & 127;     // batch lane

    // stage edge lists for the 4 relations of this dst
    {
        const int r = fs;
        const int j = b;
        const int c = cnt[dst * Rn + r];
        const int o = off[dst * Rn + r];
        if (j == 0) { tcnt[r] = c; scnt[r] = (c < 128) ? c : 128; }
        if (j < c && j < 128) srcs[r][j] = csr[o + j];
    }
    __syncthreads();

    const int f0 = fs * 11;
    const int nf = (fs == 3) ? 10 : 11;

    // a[r][k]: r=0..3 relation sums, r=4 self(root) row
    float a[5][11];
    #pragma unroll
    for (int rr = 0; rr < 5; ++rr)
        #pragma unroll
        for (int k = 0; k < 11; ++k) a[rr][k] = 0.f;

    #pragma unroll
    for (int r = 0; r < Rn; ++r) {
        const int c = scnt[r];
        for (int j = 0; j < c; ++j) {
            const int src = srcs[r][j];
            const float* xp = xT + ((size_t)src * FSn + f0) * Bn + b;
            #pragma unroll
            for (int k = 0; k < 11; ++k)
                if (k < nf) a[r][k] += xp[(size_t)k * Bn];
        }
    }
    {   // self row
        const float* xp = xT + ((size_t)dst * FSn + f0) * Bn + b;
        #pragma unroll
        for (int k = 0; k < 11; ++k)
            if (k < nf) a[4][k] += xp[(size_t)k * Bn];
    }
    #pragma unroll
    for (int r = 0; r < Rn; ++r) {
        const int c = tcnt[r];
        const float iv = (c > 0) ? 1.f / (float)c : 0.f;
        #pragma unroll
        for (int k = 0; k < 11; ++k) a[r][k] *= iv;
    }

    // register-tiled transform: accg[g] += a[rr][k] * w[rr][f][g]
    // w reads are wave-uniform -> scalar loads (SALU), no VALU/LDS cost.
    float accg[FSn];
    #pragma unroll
    for (int g = 0; g < FSn; ++g) accg[g] = 0.f;
    float psum = 0.f;  // partial of sum_f w_fin[1+f] * x[dst][f]

    #pragma unroll
    for (int k = 0; k < 11; ++k) {
        if (k < nf) {
            const int f = f0 + k;
            #pragma unroll
            for (int rr = 0; rr < 5; ++rr) {
                const float av = a[rr][k];
                const float* wrow = (rr < 4)
                    ? (w_rel + ((size_t)rr * FSn + f) * FSn)
                    : (w_root + (size_t)f * FSn);
                #pragma unroll
                for (int g = 0; g < FSn; ++g) accg[g] += av * wrow[g];
            }
            psum += a[4][k] * w_fin[1 + f];
        }
    }

    // reduce the 4 f-groups through LDS (3 serialized add phases)
    if (fs == 3) {
        #pragma unroll
        for (int g = 0; g < FSn; ++g) red[g][b] = accg[g];
        red[FSn][b] = psum;
    }
    __syncthreads();
    if (fs == 2) {
        #pragma unroll
        for (int g = 0; g < FSn; ++g) red[g][b] += accg[g];
        red[FSn][b] += psum;
    }
    __syncthreads();
    if (fs == 1) {
        #pragma unroll
        for (int g = 0; g < FSn; ++g) red[g][b] += accg[g];
        red[FSn][b] += psum;
    }
    __syncthreads();
    if (fs == 0) {
        float logit = b_fin[0] + w_fin[0] * la[(size_t)b * (NSELn + 1) + 1 + i]
                    + psum + red[FSn][b];
        #pragma unroll
        for (int g = 0; g < FSn; ++g) {
            float v = accg[g] + red[g][b] + b_g[g];
            v = (v > 0.f) ? v : 0.01f * v;
            logit += v * w_fin[44 + g];
        }
        logitT[(size_t)i * Bn + b] = logit;
    }
}

// ---------------------------------------------------------------------------
// Kernel 3: softmax over [0, logits(500)] per batch. Block per b.
// ---------------------------------------------------------------------------
__global__ __launch_bounds__(512) void k_softmax(const float* __restrict__ logitT,
                                                 float* __restrict__ out)
{
    __shared__ float red[512];
    const int b   = blockIdx.x;
    const int tid = threadIdx.x;

    const float l = (tid < NSELn) ? logitT[(size_t)tid * Bn + b] : -1e30f;
    red[tid] = l;
    __syncthreads();
    for (int s = 256; s > 0; s >>= 1) {
        if (tid < s) red[tid] = fmaxf(red[tid], red[tid + s]);
        __syncthreads();
    }
    const float m = fmaxf(red[0], 0.f);   // include the constant 0 logit
    __syncthreads();

    const float e = (tid < NSELn) ? expf(l - m) : 0.f;
    red[tid] = e;
    __syncthreads();
    for (int s = 256; s > 0; s >>= 1) {
        if (tid < s) red[tid] += red[tid + s];
        __syncthreads();
    }
    const float e0  = expf(-m);
    const float inv = 1.f / (red[0] + e0);

    if (tid == 0) out[(size_t)b * (NSELn + 1)] = e0 * inv;
    if (tid < NSELn) out[(size_t)b * (NSELn + 1) + 1 + tid] = l == l ? e * inv : e * inv;
}

// ---------------------------------------------------------------------------
extern "C" void kernel_launch(void* const* d_in, const int* in_sizes, int n_in,
                              void* d_out, int out_size, void* d_ws, size_t ws_size,
                              hipStream_t stream)
{
    const float* obs    = (const float*)d_in[0];
    const float* la     = (const float*)d_in[1];
    const float* w_s1   = (const float*)d_in[2];
    const float* b_s1   = (const float*)d_in[3];
    const float* w_s2   = (const float*)d_in[4];
    const float* b_s2   = (const float*)d_in[5];
    const float* w_m1   = (const float*)d_in[6];
    const float* b_m1   = (const float*)d_in[7];
    const float* w_m2   = (const float*)d_in[8];
    const float* b_m2   = (const float*)d_in[9];
    const float* w_rel  = (const float*)d_in[10];
    const float* w_root = (const float*)d_in[11];
    const float* b_g    = (const float*)d_in[12];
    const float* w_fin  = (const float*)d_in[13];
    const float* b_fin  = (const float*)d_in[14];
    const int*   ei     = (const int*)d_in[15];
    const int*   et     = (const int*)d_in[16];
    const int*   sel    = (const int*)d_in[17];
    float*       out    = (float*)d_out;

    float* x      = (float*)d_ws;               // B*NF = 5,504,000 floats
    float* xT     = x + 5504000;                // NF*B = 5,504,000 floats
    int*   cnt    = (int*)(xT + 5504000);       // 4096
    int*   offb   = cnt + 4096;                 // 4096
    int*   pos    = offb + 4096;                // 4096
    int*   csr    = pos + 4096;                 // 32000
    float* logitT = x;                          // alias: x is dead after transpose

    hipLaunchKernelGGL(k_zero,  dim3(16),  dim3(256), 0, stream, cnt, pos);
    hipLaunchKernelGGL(k_count, dim3((En + 255) / 256), dim3(256), 0, stream, ei, et, cnt);
    hipLaunchKernelGGL(k_scan,  dim3(1),   dim3(1024), 0, stream, cnt, offb);
    hipLaunchKernelGGL(k_fill,  dim3((En + 255) / 256), dim3(256), 0, stream, ei, et, offb, pos, csr);

    hipLaunchKernelGGL(k_temporal, dim3(Bn, (Nn + 63) / 64), dim3(64), 0, stream,
                       obs, w_s1, b_s1, w_s2, b_s2, w_m1, b_m1, w_m2, b_m2, x);

    hipLaunchKernelGGL(k_transpose, dim3((NFtot + 63) / 64), dim3(256), 0, stream, x, xT);

    hipLaunchKernelGGL(k_gather, dim3(NSELn), dim3(512), 0, stream,
                       xT, w_rel, w_root, b_g, w_fin, b_fin, la,
                       csr, offb, cnt, sel, logitT);

    hipLaunchKernelGGL(k_softmax, dim3(Bn), dim3(512), 0, stream, logitT, out);
}

// Round 3
// 258.420 us; speedup vs baseline: 3.0901x; 1.3672x over previous
//
#include <hip/hip_runtime.h>
#include <math.h>

#define Bn 128
#define Nn 1000
#define Tn 50
#define En 32000
#define Rn 4
#define FSn 43
#define NSELn 500
#define NFtot (Nn * FSn)   // 43000

// ---------------------------------------------------------------------------
// Kernel 1: fused temporal feature extraction, 4-wave cooperative blocks.
// Block = 256 threads = 4 waves, covering 64 nodes of one batch b.
// Wave roles (t-split of the reductions):
//   w0: short conv t in [0,24)  + long max t in [0,25)   (+ biases)
//   w1: short conv t in [24,48) + long max t in [25,50)
//   w2: mid   conv t in [0,15)                            (+ biases)
//   w3: mid   conv t in [15,30)
// Partials exchanged via the (dead) obs LDS tile.
// LDS: 3*64*51 floats = 39168 B -> 4 blocks/CU = 16 waves/CU.
// ---------------------------------------------------------------------------
__global__ __launch_bounds__(256, 4) void k_temporal(
    const float* __restrict__ obs,
    const float* __restrict__ w_s1, const float* __restrict__ b_s1,
    const float* __restrict__ w_s2, const float* __restrict__ b_s2,
    const float* __restrict__ w_m1, const float* __restrict__ b_m1,
    const float* __restrict__ w_m2, const float* __restrict__ b_m2,
    float* __restrict__ x)
{
    __shared__ float lds[3 * 64 * 51];

    const int b     = blockIdx.x;
    const int tile0 = blockIdx.y * 64;
    const int tid   = threadIdx.x;
    const int lane  = tid & 63;
    const int w     = __builtin_amdgcn_readfirstlane(tid >> 6);
    const int nrows = (Nn - tile0) < 64 ? (Nn - tile0) : 64;

    // ---- cooperative stage: obs[b][c][tile0..tile0+nrows)[0..50) ----
    for (int c = 0; c < 3; ++c) {
        const float* srcp = obs + ((size_t)(b * 3 + c) * Nn + tile0) * Tn;
        for (int idx = tid; idx < nrows * Tn; idx += 256) {
            const int r = idx / Tn;
            const int t = idx - r * Tn;
            lds[(c * 64 + r) * 51 + t] = srcp[idx];
        }
    }
    __syncthreads();

    const int rb0 = (0 * 64 + lane) * 51;
    const int rb1 = (1 * 64 + lane) * 51;
    const int rb2 = (2 * 64 + lane) * 51;

    float acc[20];
    float mx0 = -1e30f, mx1 = -1e30f, mx2 = -1e30f;

    if (w < 2) {
        // ---------------- short path partial ----------------
        #pragma unroll
        for (int o = 0; o < 20; ++o) acc[o] = (w == 0) ? b_s2[o] : 0.f;

        const float s10 = b_s1[0], s11 = b_s1[1], s12 = b_s1[2];
        const int t0 = w * 24;

        #pragma unroll 1
        for (int t = t0; t < t0 + 24; ++t) {
            float v0 = s10, v1 = s11, v2 = s12;
            #pragma unroll
            for (int c = 0; c < 3; ++c) {
                const int base = (c * 64 + lane) * 51 + t;
                const float o0 = lds[base + 0];
                const float o1 = lds[base + 1];
                const float o2 = lds[base + 2];
                v0 += o0 * w_s1[(0 * 3 + c) * 3 + 0] + o1 * w_s1[(0 * 3 + c) * 3 + 1] + o2 * w_s1[(0 * 3 + c) * 3 + 2];
                v1 += o0 * w_s1[(1 * 3 + c) * 3 + 0] + o1 * w_s1[(1 * 3 + c) * 3 + 1] + o2 * w_s1[(1 * 3 + c) * 3 + 2];
                v2 += o0 * w_s1[(2 * 3 + c) * 3 + 0] + o1 * w_s1[(2 * 3 + c) * 3 + 1] + o2 * w_s1[(2 * 3 + c) * 3 + 2];
            }
            v0 = fmaxf(v0, 0.f); v1 = fmaxf(v1, 0.f); v2 = fmaxf(v2, 0.f);
            #pragma unroll
            for (int o = 0; o < 20; ++o) {
                acc[o] += v0 * w_s2[(o * 3 + 0) * 48 + t]
                        + v1 * w_s2[(o * 3 + 1) * 48 + t]
                        + v2 * w_s2[(o * 3 + 2) * 48 + t];
            }
        }

        // ---------------- long path partial ----------------
        const int l0 = w * 25;
        #pragma unroll 1
        for (int t = l0; t < l0 + 25; ++t) {
            mx0 = fmaxf(mx0, lds[rb0 + t]);
            mx1 = fmaxf(mx1, lds[rb1 + t]);
            mx2 = fmaxf(mx2, lds[rb2 + t]);
        }
    } else {
        // ---------------- mid path partial ----------------
        #pragma unroll
        for (int o = 0; o < 20; ++o) acc[o] = (w == 2) ? b_m2[o] : 0.f;

        const float m10 = b_m1[0], m11 = b_m1[1], m12 = b_m1[2];
        const int t0 = (w - 2) * 15;

        #pragma unroll 1
        for (int t = t0; t < t0 + 15; ++t) {
            float u0 = m10, u1 = m11, u2 = m12;
            #pragma unroll
            for (int c = 0; c < 3; ++c) {
                const int base = (c * 64 + lane) * 51 + t;
                #pragma unroll
                for (int d = 0; d < 21; ++d) {
                    const float ov = lds[base + d];
                    u0 += ov * w_m1[(0 * 3 + c) * 21 + d];
                    u1 += ov * w_m1[(1 * 3 + c) * 21 + d];
                    u2 += ov * w_m1[(2 * 3 + c) * 21 + d];
                }
            }
            u0 = fmaxf(u0, 0.f); u1 = fmaxf(u1, 0.f); u2 = fmaxf(u2, 0.f);
            #pragma unroll
            for (int o = 0; o < 20; ++o) {
                acc[o] += u0 * w_m2[(o * 3 + 0) * 30 + t]
                        + u1 * w_m2[(o * 3 + 1) * 30 + t]
                        + u2 * w_m2[(o * 3 + 2) * 30 + t];
            }
        }
    }

    // ---- exchange partials via the (now dead) obs tile ----
    __syncthreads();
    float* pshort = lds;               // [20][64]
    float* plong  = lds + 20 * 64;     // [3][64]
    float* pmid   = lds + 23 * 64;     // [20][64]

    if (w == 1) {
        #pragma unroll
        for (int o = 0; o < 20; ++o) pshort[o * 64 + lane] = acc[o];
        plong[0 * 64 + lane] = mx0;
        plong[1 * 64 + lane] = mx1;
        plong[2 * 64 + lane] = mx2;
    }
    if (w == 3) {
        #pragma unroll
        for (int o = 0; o < 20; ++o) pmid[o * 64 + lane] = acc[o];
    }
    __syncthreads();

    if (lane < nrows) {
        float* xp = x + ((size_t)b * Nn + tile0 + lane) * FSn;
        if (w == 0) {
            #pragma unroll
            for (int o = 0; o < 20; ++o)
                xp[o] = fmaxf(acc[o] + pshort[o * 64 + lane], 0.f);
            xp[40] = fmaxf(fmaxf(mx0, plong[0 * 64 + lane]), 0.f);
            xp[41] = fmaxf(fmaxf(mx1, plong[1 * 64 + lane]), 0.f);
            xp[42] = fmaxf(fmaxf(mx2, plong[2 * 64 + lane]), 0.f);
        } else if (w == 2) {
            #pragma unroll
            for (int o = 0; o < 20; ++o)
                xp[20 + o] = fmaxf(acc[o] + pmid[o * 64 + lane], 0.f);
        }
    }
}

// ---------------------------------------------------------------------------
// Transpose x[b][nf] (128 x 43000) -> xT[nf][b] (43000 x 128)
// ---------------------------------------------------------------------------
__global__ __launch_bounds__(256) void k_transpose(const float* __restrict__ x,
                                                   float* __restrict__ xT)
{
    __shared__ float tile[64][129];
    const int c0  = blockIdx.x * 64;
    const int tid = threadIdx.x;

    const int j  = tid & 63;
    const int bs = tid >> 6;
    for (int bb = bs; bb < Bn; bb += 4) {
        int c = c0 + j;
        if (c < NFtot) tile[j][bb] = x[(size_t)bb * NFtot + c];
    }
    __syncthreads();

    const int b  = tid & 127;
    for (int jj = (tid >> 7); jj < 64; jj += 2) {
        int c = c0 + jj;
        if (c < NFtot) xT[(size_t)c * Bn + b] = tile[jj][b];
    }
}

// ---------------------------------------------------------------------------
// CSR build
// ---------------------------------------------------------------------------
__global__ void k_zero(int* __restrict__ cnt, int* __restrict__ pos)
{
    int i = blockIdx.x * blockDim.x + threadIdx.x;
    if (i < 4096) { cnt[i] = 0; pos[i] = 0; }
}

__global__ void k_count(const int* __restrict__ ei, const int* __restrict__ et,
                        int* __restrict__ cnt)
{
    int e = blockIdx.x * blockDim.x + threadIdx.x;
    if (e < En) {
        int dst = ei[En + e];
        atomicAdd(&cnt[dst * Rn + et[e]], 1);
    }
}

__global__ __launch_bounds__(1024) void k_scan(const int* __restrict__ cnt,
                                               int* __restrict__ off)
{
    __shared__ int sums[1024];
    int tid = threadIdx.x;
    int base = tid * 4;
    int c[4];
    int ts = 0;
    #pragma unroll
    for (int k = 0; k < 4; ++k) {
        int i = base + k;
        c[k] = (i < Nn * Rn) ? cnt[i] : 0;
        ts += c[k];
    }
    sums[tid] = ts;
    __syncthreads();
    for (int d = 1; d < 1024; d <<= 1) {
        int t = 0;
        if (tid >= d) t = sums[tid - d];
        __syncthreads();
        sums[tid] += t;
        __syncthreads();
    }
    int excl = sums[tid] - ts;
    #pragma unroll
    for (int k = 0; k < 4; ++k) {
        int i = base + k;
        off[i] = excl;
        excl += c[k];
    }
}

__global__ void k_fill(const int* __restrict__ ei, const int* __restrict__ et,
                       const int* __restrict__ off, int* __restrict__ pos,
                       int* __restrict__ csr)
{
    int e = blockIdx.x * blockDim.x + threadIdx.x;
    if (e < En) {
        int src = ei[e];
        int dst = ei[En + e];
        int seg = dst * Rn + et[e];
        int p = atomicAdd(&pos[seg], 1);
        csr[off[seg] + p] = src;
    }
}

// ---------------------------------------------------------------------------
// Kernel 2: gather + relational transform + root + leaky + final projection.
// One block per SELECTED dst node; lanes = batch b. 512 thr = 4 f-groups x 128 b.
// ---------------------------------------------------------------------------
__global__ __launch_bounds__(512) void k_gather(
    const float* __restrict__ xT,
    const float* __restrict__ w_rel, const float* __restrict__ w_root,
    const float* __restrict__ b_g,
    const float* __restrict__ w_fin, const float* __restrict__ b_fin,
    const float* __restrict__ la,
    const int* __restrict__ csr, const int* __restrict__ off,
    const int* __restrict__ cnt, const int* __restrict__ sel,
    float* __restrict__ logitT)
{
    __shared__ int   srcs[Rn][128];
    __shared__ int   scnt[Rn];
    __shared__ int   tcnt[Rn];
    __shared__ float red[FSn + 1][Bn];

    const int i   = blockIdx.x;
    const int dst = sel[i];
    const int tid = threadIdx.x;
    const int fs  = tid >> 7;
    const int b   = tid & 127;

    {
        const int r = fs;
        const int j = b;
        const int c = cnt[dst * Rn + r];
        const int o = off[dst * Rn + r];
        if (j == 0) { tcnt[r] = c; scnt[r] = (c < 128) ? c : 128; }
        if (j < c && j < 128) srcs[r][j] = csr[o + j];
    }
    __syncthreads();

    const int f0 = fs * 11;
    const int nf = (fs == 3) ? 10 : 11;

    float a[5][11];
    #pragma unroll
    for (int rr = 0; rr < 5; ++rr)
        #pragma unroll
        for (int k = 0; k < 11; ++k) a[rr][k] = 0.f;

    #pragma unroll
    for (int r = 0; r < Rn; ++r) {
        const int c = scnt[r];
        for (int j = 0; j < c; ++j) {
            const int src = srcs[r][j];
            const float* xp = xT + ((size_t)src * FSn + f0) * Bn + b;
            #pragma unroll
            for (int k = 0; k < 11; ++k)
                if (k < nf) a[r][k] += xp[(size_t)k * Bn];
        }
    }
    {
        const float* xp = xT + ((size_t)dst * FSn + f0) * Bn + b;
        #pragma unroll
        for (int k = 0; k < 11; ++k)
            if (k < nf) a[4][k] += xp[(size_t)k * Bn];
    }
    #pragma unroll
    for (int r = 0; r < Rn; ++r) {
        const int c = tcnt[r];
        const float iv = (c > 0) ? 1.f / (float)c : 0.f;
        #pragma unroll
        for (int k = 0; k < 11; ++k) a[r][k] *= iv;
    }

    float accg[FSn];
    #pragma unroll
    for (int g = 0; g < FSn; ++g) accg[g] = 0.f;
    float psum = 0.f;

    #pragma unroll
    for (int k = 0; k < 11; ++k) {
        if (k < nf) {
            const int f = f0 + k;
            #pragma unroll
            for (int rr = 0; rr < 5; ++rr) {
                const float av = a[rr][k];
                const float* wrow = (rr < 4)
                    ? (w_rel + ((size_t)rr * FSn + f) * FSn)
                    : (w_root + (size_t)f * FSn);
                #pragma unroll
                for (int g = 0; g < FSn; ++g) accg[g] += av * wrow[g];
            }
            psum += a[4][k] * w_fin[1 + f];
        }
    }

    if (fs == 3) {
        #pragma unroll
        for (int g = 0; g < FSn; ++g) red[g][b] = accg[g];
        red[FSn][b] = psum;
    }
    __syncthreads();
    if (fs == 2) {
        #pragma unroll
        for (int g = 0; g < FSn; ++g) red[g][b] += accg[g];
        red[FSn][b] += psum;
    }
    __syncthreads();
    if (fs == 1) {
        #pragma unroll
        for (int g = 0; g < FSn; ++g) red[g][b] += accg[g];
        red[FSn][b] += psum;
    }
    __syncthreads();
    if (fs == 0) {
        float logit = b_fin[0] + w_fin[0] * la[(size_t)b * (NSELn + 1) + 1 + i]
                    + psum + red[FSn][b];
        #pragma unroll
        for (int g = 0; g < FSn; ++g) {
            float v = accg[g] + red[g][b] + b_g[g];
            v = (v > 0.f) ? v : 0.01f * v;
            logit += v * w_fin[44 + g];
        }
        logitT[(size_t)i * Bn + b] = logit;
    }
}

// ---------------------------------------------------------------------------
// Kernel 3: softmax over [0, logits(500)] per batch. Block per b.
// ---------------------------------------------------------------------------
__global__ __launch_bounds__(512) void k_softmax(const float* __restrict__ logitT,
                                                 float* __restrict__ out)
{
    __shared__ float red[512];
    const int b   = blockIdx.x;
    const int tid = threadIdx.x;

    const float l = (tid < NSELn) ? logitT[(size_t)tid * Bn + b] : -1e30f;
    red[tid] = l;
    __syncthreads();
    for (int s = 256; s > 0; s >>= 1) {
        if (tid < s) red[tid] = fmaxf(red[tid], red[tid + s]);
        __syncthreads();
    }
    const float m = fmaxf(red[0], 0.f);
    __syncthreads();

    const float e = (tid < NSELn) ? expf(l - m) : 0.f;
    red[tid] = e;
    __syncthreads();
    for (int s = 256; s > 0; s >>= 1) {
        if (tid < s) red[tid] += red[tid + s];
        __syncthreads();
    }
    const float e0  = expf(-m);
    const float inv = 1.f / (red[0] + e0);

    if (tid == 0) out[(size_t)b * (NSELn + 1)] = e0 * inv;
    if (tid < NSELn) out[(size_t)b * (NSELn + 1) + 1 + tid] = e * inv;
}

// ---------------------------------------------------------------------------
extern "C" void kernel_launch(void* const* d_in, const int* in_sizes, int n_in,
                              void* d_out, int out_size, void* d_ws, size_t ws_size,
                              hipStream_t stream)
{
    const float* obs    = (const float*)d_in[0];
    const float* la     = (const float*)d_in[1];
    const float* w_s1   = (const float*)d_in[2];
    const float* b_s1   = (const float*)d_in[3];
    const float* w_s2   = (const float*)d_in[4];
    const float* b_s2   = (const float*)d_in[5];
    const float* w_m1   = (const float*)d_in[6];
    const float* b_m1   = (const float*)d_in[7];
    const float* w_m2   = (const float*)d_in[8];
    const float* b_m2   = (const float*)d_in[9];
    const float* w_rel  = (const float*)d_in[10];
    const float* w_root = (const float*)d_in[11];
    const float* b_g    = (const float*)d_in[12];
    const float* w_fin  = (const float*)d_in[13];
    const float* b_fin  = (const float*)d_in[14];
    const int*   ei     = (const int*)d_in[15];
    const int*   et     = (const int*)d_in[16];
    const int*   sel    = (const int*)d_in[17];
    float*       out    = (float*)d_out;

    float* x      = (float*)d_ws;               // B*NF floats
    float* xT     = x + 5504000;                // NF*B floats
    int*   cnt    = (int*)(xT + 5504000);       // 4096
    int*   offb   = cnt + 4096;                 // 4096
    int*   pos    = offb + 4096;                // 4096
    int*   csr    = pos + 4096;                 // 32000
    float* logitT = x;                          // alias: x dead after transpose

    hipLaunchKernelGGL(k_zero,  dim3(16),  dim3(256), 0, stream, cnt, pos);
    hipLaunchKernelGGL(k_count, dim3((En + 255) / 256), dim3(256), 0, stream, ei, et, cnt);
    hipLaunchKernelGGL(k_scan,  dim3(1),   dim3(1024), 0, stream, cnt, offb);
    hipLaunchKernelGGL(k_fill,  dim3((En + 255) / 256), dim3(256), 0, stream, ei, et, offb, pos, csr);

    hipLaunchKernelGGL(k_temporal, dim3(Bn, (Nn + 63) / 64), dim3(256), 0, stream,
                       obs, w_s1, b_s1, w_s2, b_s2, w_m1, b_m1, w_m2, b_m2, x);

    hipLaunchKernelGGL(k_transpose, dim3((NFtot + 63) / 64), dim3(256), 0, stream, x, xT);

    hipLaunchKernelGGL(k_gather, dim3(NSELn), dim3(512), 0, stream,
                       xT, w_rel, w_root, b_g, w_fin, b_fin, la,
                       csr, offb, cnt, sel, logitT);

    hipLaunchKernelGGL(k_softmax, dim3(Bn), dim3(512), 0, stream, logitT, out);
}